// Round 1
// baseline (3099.456 us; speedup 1.0000x reference)
//
#include <hip/hip_runtime.h>

// Problem constants (match reference): B=32, N=M=128, D=256, WEIGHT=1.0
#define Bc 32
#define Nn 128
#define Dd 256

// ---------------------------------------------------------------------------
// Kernel 1: pairwise MSE cost.  cost[b,i,j] = sum_d (p[b,i,d]-g[b,j,d])^2 / D
// One wave (64 threads) per (b,i) row. Lane t holds float4 of p[b,i] (64*4=256).
// Loop over j: coalesced float4 load of g row, 4 squared diffs, wave reduce.
// ---------------------------------------------------------------------------
__global__ __launch_bounds__(64) void cost_kernel(const float* __restrict__ P,
                                                  const float* __restrict__ G,
                                                  float* __restrict__ C) {
    const int b = blockIdx.y;
    const int i = blockIdx.x;
    const int t = threadIdx.x;

    const float4 pv = ((const float4*)(P + ((size_t)b * Nn + i) * Dd))[t];
    const float4* g4 = (const float4*)(G + (size_t)b * Nn * Dd);
    float* crow = C + ((size_t)b * Nn + i) * Nn;

    for (int j = 0; j < Nn; j += 2) {
        // two j's in flight for a little ILP in the shuffle chains
        float4 gv0 = g4[(size_t)j * 64 + t];
        float4 gv1 = g4[(size_t)(j + 1) * 64 + t];
        float dx0 = pv.x - gv0.x, dy0 = pv.y - gv0.y, dz0 = pv.z - gv0.z, dw0 = pv.w - gv0.w;
        float dx1 = pv.x - gv1.x, dy1 = pv.y - gv1.y, dz1 = pv.z - gv1.z, dw1 = pv.w - gv1.w;
        float s0 = dx0 * dx0 + dy0 * dy0 + dz0 * dz0 + dw0 * dw0;
        float s1 = dx1 * dx1 + dy1 * dy1 + dz1 * dz1 + dw1 * dw1;
#pragma unroll
        for (int off = 32; off; off >>= 1) {
            s0 += __shfl_xor(s0, off);
            s1 += __shfl_xor(s1, off);
        }
        if (t == 0) {
            crow[j]     = s0 * (1.0f / (float)Dd);
            crow[j + 1] = s1 * (1.0f / (float)Dd);
        }
    }
}

// ---------------------------------------------------------------------------
// Kernel 2: Jonker-Volgenant Hungarian, one single-wave block per batch.
// Lane t owns columns jA=t+1, jB=t+65 (1-indexed, 0 = virtual start column).
// Column state (minv, v, used) lives in registers; u[], p[], way[] in LDS.
// Potentials in double to mirror the reference's float64 host Hungarian.
// The optimal total cost is unique, so tie-breaking differences vs numpy are
// harmless for the loss value.
// ---------------------------------------------------------------------------
__global__ __launch_bounds__(64) void hungarian_kernel(const float* __restrict__ Call,
                                                       float* __restrict__ out) {
    const int b = blockIdx.x;
    const int tid = threadIdx.x;
    const float* C = Call + (size_t)b * Nn * Nn;

    __shared__ double u_sh[Nn + 1];
    __shared__ int p_sh[Nn + 1];
    __shared__ int way_sh[Nn + 1];

    for (int k = tid; k <= Nn; k += 64) {
        u_sh[k] = 0.0;
        p_sh[k] = 0;
        way_sh[k] = 0;
    }

    const int jA = tid + 1;
    const int jB = tid + 65;
    double vA = 0.0, vB = 0.0;
    const double INF = __builtin_huge_val();

    __syncthreads();

    for (int i = 1; i <= Nn; ++i) {
        if (tid == 0) p_sh[0] = i;
        double minvA = INF, minvB = INF;
        bool usedA = false, usedB = false, used0 = false;
        int j0 = 0;

        for (;;) {
            // used[j0] = true (marked before the relax step, per reference)
            if (j0 == 0) {
                if (tid == 0) used0 = true;
            } else if (tid == j0 - 1) {
                usedA = true;
            } else if (tid == j0 - 65) {
                usedB = true;
            }
            __syncthreads();  // orders prior iteration's u-scatter & p[0] write

            const int i0 = p_sh[j0];          // uniform broadcast read
            const double ui0 = u_sh[i0];
            const float* crow = C + (size_t)(i0 - 1) * Nn;

            // relax free owned columns
            if (!usedA) {
                double cur = (double)crow[tid] - ui0 - vA;
                if (cur < minvA) { minvA = cur; way_sh[jA] = j0; }
            }
            if (!usedB) {
                double cur = (double)crow[tid + 64] - ui0 - vB;
                if (cur < minvB) { minvB = cur; way_sh[jB] = j0; }
            }

            // argmin over free columns (butterfly -> every lane has result)
            double bv; int bj;
            {
                double mA = usedA ? INF : minvA;
                double mB = usedB ? INF : minvB;
                if (mA <= mB) { bv = mA; bj = jA; }
                else          { bv = mB; bj = jB; }
            }
#pragma unroll
            for (int off = 32; off; off >>= 1) {
                double ov = __shfl_xor(bv, off);
                int    oj = __shfl_xor(bj, off);
                if (ov < bv || (ov == bv && oj < bj)) { bv = ov; bj = oj; }
            }
            const double delta = bv;
            const int j1 = bj;

            // dual updates: u[p[j]] += delta over used j (distinct rows -> no
            // write conflicts), v[used] -= delta, minv[free] -= delta
            if (used0 && tid == 0) u_sh[p_sh[0]] += delta;
            if (usedA) { u_sh[p_sh[jA]] += delta; vA -= delta; }
            else       { minvA -= delta; }
            if (usedB) { u_sh[p_sh[jB]] += delta; vB -= delta; }
            else       { minvB -= delta; }

            j0 = j1;
            if (p_sh[j0] == 0) break;  // p untouched inside the loop
        }

        __syncthreads();  // way_sh writes visible to lane 0
        if (tid == 0) {
            int j = j0;
            while (j) {
                int jn = way_sh[j];
                p_sh[j] = p_sh[jn];
                j = jn;
            }
        }
        __syncthreads();  // p_sh updates visible to all
    }

    // matched-cost gather: column j assigned to row p[j]-1
    double total = (double)C[(size_t)(p_sh[jA] - 1) * Nn + tid]
                 + (double)C[(size_t)(p_sh[jB] - 1) * Nn + tid + 64];
#pragma unroll
    for (int off = 32; off; off >>= 1) total += __shfl_xor(total, off);

    if (tid == 0) {
        // loss = sum_b (total_b / N) / B * WEIGHT
        atomicAdd(out, (float)(total / ((double)Nn * (double)Bc)));
    }
}

extern "C" void kernel_launch(void* const* d_in, const int* in_sizes, int n_in,
                              void* d_out, int out_size, void* d_ws, size_t ws_size,
                              hipStream_t stream) {
    const float* P = (const float*)d_in[0];   // batch_prediction  [32,128,256] f32
    const float* G = (const float*)d_in[1];   // batch_groundtruth [32,128,256] f32
    float* out = (float*)d_out;               // [1] f32
    float* C = (float*)d_ws;                  // cost scratch: 32*128*128 f32 = 2 MB

    hipMemsetAsync(out, 0, sizeof(float), stream);

    dim3 gcost(Nn, Bc);
    cost_kernel<<<gcost, 64, 0, stream>>>(P, G, C);
    hungarian_kernel<<<Bc, 64, 0, stream>>>(C, out);
}

// Round 2
// 1035.903 us; speedup vs baseline: 2.9920x; 2.9920x over previous
//
#include <hip/hip_runtime.h>
#include <float.h>

// Problem constants (match reference): B=32, N=M=128, D=256, WEIGHT=1.0
#define Bc 32
#define Nn 128
#define Dd 256

// ---------------------------------------------------------------------------
// Kernel 1: pairwise MSE cost.  cost[b,i,j] = sum_d (p[b,i,d]-g[b,j,d])^2 / D
// One wave (64 threads) per (b,i) row. Lane t holds float4 of p[b,i] (64*4=256).
// ---------------------------------------------------------------------------
__global__ __launch_bounds__(64) void cost_kernel(const float* __restrict__ P,
                                                  const float* __restrict__ G,
                                                  float* __restrict__ C) {
    const int b = blockIdx.y;
    const int i = blockIdx.x;
    const int t = threadIdx.x;

    const float4 pv = ((const float4*)(P + ((size_t)b * Nn + i) * Dd))[t];
    const float4* g4 = (const float4*)(G + (size_t)b * Nn * Dd);
    float* crow = C + ((size_t)b * Nn + i) * Nn;

    for (int j = 0; j < Nn; j += 2) {
        float4 gv0 = g4[(size_t)j * 64 + t];
        float4 gv1 = g4[(size_t)(j + 1) * 64 + t];
        float dx0 = pv.x - gv0.x, dy0 = pv.y - gv0.y, dz0 = pv.z - gv0.z, dw0 = pv.w - gv0.w;
        float dx1 = pv.x - gv1.x, dy1 = pv.y - gv1.y, dz1 = pv.z - gv1.z, dw1 = pv.w - gv1.w;
        float s0 = dx0 * dx0 + dy0 * dy0 + dz0 * dz0 + dw0 * dw0;
        float s1 = dx1 * dx1 + dy1 * dy1 + dz1 * dz1 + dw1 * dw1;
#pragma unroll
        for (int off = 32; off; off >>= 1) {
            s0 += __shfl_xor(s0, off);
            s1 += __shfl_xor(s1, off);
        }
        if (t == 0) {
            crow[j]     = s0 * (1.0f / (float)Dd);
            crow[j + 1] = s1 * (1.0f / (float)Dd);
        }
    }
}

// ---------------------------------------------------------------------------
// Full-wave f32 min via DPP: row_ror 1/2/4/8 (all source lanes valid -> no
// bound_ctrl ambiguity) gives per-16-row min in every lane; row_bcast15/31
// fold rows; the lane-63 result only flows through valid-source lanes.
// min(x,x) idempotence makes masks/double-combines harmless.
// ---------------------------------------------------------------------------
#define DPP_MIN_STEP(x, ctrl)                                                        \
    {                                                                                \
        int _y = __builtin_amdgcn_update_dpp(0x7f7fffff, __float_as_int(x), (ctrl),  \
                                             0xf, 0xf, false);                       \
        (x) = fminf((x), __int_as_float(_y));                                        \
    }

__device__ __forceinline__ float wave_min_lane63(float x) {
    DPP_MIN_STEP(x, 0x121);  // row_ror:1
    DPP_MIN_STEP(x, 0x122);  // row_ror:2
    DPP_MIN_STEP(x, 0x124);  // row_ror:4
    DPP_MIN_STEP(x, 0x128);  // row_ror:8
    DPP_MIN_STEP(x, 0x142);  // row_bcast:15
    DPP_MIN_STEP(x, 0x143);  // row_bcast:31
    return x;                // lane 63 holds min of all 64 lanes
}

__device__ __forceinline__ float readlane_f(float v, int lane) {
    return __int_as_float(__builtin_amdgcn_readlane(__float_as_int(v), lane));
}

// ---------------------------------------------------------------------------
// Kernel 2: Jonker-Volgenant Hungarian, one single-wave block per batch.
// Cost matrix in LDS (row-major, conflict-free 2-way access).
// ALL algorithm state in registers:
//   lane t owns columns jA=t+1, jB=t+65 : v, minv, way, used, p (assigned row),
//                                          w = u[p[j]] (cached row potential)
//   lane t owns rows    t+1,  t+65      : u, rowUsed (flag: row in current tree)
// Cross-lane traffic = v_readlane with uniform lane index + ballots + DPP min.
// No LDS state, no __syncthreads in the hot loop (single wave, lockstep).
// f32 potentials: optimal total is unique; rounding-induced assignment
// differences change the loss by ~1e-4 << 3.4e-2 threshold.
// ---------------------------------------------------------------------------
__global__ __launch_bounds__(64) void hungarian_kernel(const float* __restrict__ Call,
                                                       float* __restrict__ out) {
    const int b = blockIdx.x;
    const int t = threadIdx.x;

    __shared__ float Csh[Nn * Nn];  // 64 KB

    // stage this batch's cost matrix into LDS (coalesced float4)
    {
        const float4* src = (const float4*)(Call + (size_t)b * Nn * Nn);
        float4* dst = (float4*)Csh;
#pragma unroll
        for (int k = 0; k < (Nn * Nn / 4) / 64; ++k)
            dst[k * 64 + t] = src[k * 64 + t];
    }
    __syncthreads();

    // persistent state
    float vA = 0.0f, vB = 0.0f;   // column potentials
    float uA = 0.0f, uB = 0.0f;   // row potentials (rows t+1, t+65)
    float wA = 0.0f, wB = 0.0f;   // w[j] = u[p[j]]
    int pA = 0, pB = 0;           // row assigned to column (0 = unassigned)

    for (int i = 1; i <= Nn; ++i) {
        float minvA = FLT_MAX, minvB = FLT_MAX;
        int wayA = 0, wayB = 0;
        bool usedA = false, usedB = false;
        bool rUA = false, rUB = false;  // row in alternating tree

        // virtual column 0: p[0]=i, used -> row i accumulates deltas
        {
            int r = i - 1;
            if (t == (r & 63)) { if ((r >> 6) == 0) rUA = true; else rUB = true; }
        }

        int s_j0 = 0;
        int s_i0 = i;        // p[j0]
        float s_u = 0.0f;    // u[i] == 0 for a fresh row (rows settle in order)
        int s_j1;

        for (;;) {
            // ---- relax free columns against row s_i0 ----
            const float* crow = &Csh[(s_i0 - 1) * Nn];
            float c0 = crow[t];
            float c1 = crow[t + 64];
            if (!usedA) {
                float cur = c0 - s_u - vA;
                if (cur < minvA) { minvA = cur; wayA = s_j0; }
            }
            if (!usedB) {
                float cur = c1 - s_u - vB;
                if (cur < minvB) { minvB = cur; wayB = s_j0; }
            }

            // ---- exact argmin over free columns ----
            float mA = usedA ? FLT_MAX : minvA;
            float mB = usedB ? FLT_MAX : minvB;
            float m = fminf(mA, mB);
            float r63 = wave_min_lane63(m);
            float s_delta = readlane_f(r63, 63);
            unsigned long long ba = __ballot(mA == s_delta);
            unsigned long long bb = __ballot(mB == s_delta);
            s_j1 = ba ? __ffsll(ba) : (__ffsll(bb) + 64);  // lowest-index tie-break

            // ---- dual updates ----
            if (usedA) { vA -= s_delta; wA += s_delta; } else { minvA -= s_delta; }
            if (usedB) { vB -= s_delta; wB += s_delta; } else { minvB -= s_delta; }
            if (rUA) uA += s_delta;
            if (rUB) uB += s_delta;

            // ---- advance to column j1 ----
            int lane1 = (s_j1 - 1) & 63;
            int slot1 = (s_j1 - 1) >> 6;
            int ptmp = slot1 ? pB : pA;
            int s_p = __builtin_amdgcn_readlane(ptmp, lane1);
            float wtmp = slot1 ? wB : wA;
            float s_w = readlane_f(wtmp, lane1);

            if (s_p == 0) break;  // augmenting path found at column s_j1

            if (t == lane1) { if (slot1 == 0) usedA = true; else usedB = true; }
            {
                int r = s_p - 1;
                if (t == (r & 63)) { if ((r >> 6) == 0) rUA = true; else rUB = true; }
            }
            s_j0 = s_j1;
            s_i0 = s_p;
            s_u = s_w;   // u[p[j1]] (pre-update value, matching reference order)
        }

        // ---- augment along way[] chain (uniform serial walk) ----
        int s_j = s_j1;
        while (s_j) {
            int lane = (s_j - 1) & 63;
            int slot = (s_j - 1) >> 6;
            int wy = slot ? wayB : wayA;
            int s_jprev = __builtin_amdgcn_readlane(wy, lane);
            int s_pnew;
            if (s_jprev == 0) {
                s_pnew = i;  // p[0] = i
            } else {
                int lp = (s_jprev - 1) & 63;
                int sp = (s_jprev - 1) >> 6;
                int pt = sp ? pB : pA;
                s_pnew = __builtin_amdgcn_readlane(pt, lp);
            }
            // refresh w[s_j] = u[s_pnew] (u fully updated for this row already)
            int rl = (s_pnew - 1) & 63;
            int rs = (s_pnew - 1) >> 6;
            float ut = rs ? uB : uA;
            float s_unew = readlane_f(ut, rl);
            if (t == lane) {
                if (slot == 0) { pA = s_pnew; wA = s_unew; }
                else           { pB = s_pnew; wB = s_unew; }
            }
            s_j = s_jprev;
        }
    }

    // ---- gather matched costs: column jA=t+1 -> row pA, etc. ----
    float tot = Csh[(pA - 1) * Nn + t] + Csh[(pB - 1) * Nn + t + 64];
#pragma unroll
    for (int off = 32; off; off >>= 1) tot += __shfl_xor(tot, off);

    if (t == 0) {
        // loss = sum_b (total_b / N) / B * WEIGHT
        atomicAdd(out, tot * (1.0f / ((float)Nn * (float)Bc)));
    }
}

extern "C" void kernel_launch(void* const* d_in, const int* in_sizes, int n_in,
                              void* d_out, int out_size, void* d_ws, size_t ws_size,
                              hipStream_t stream) {
    const float* P = (const float*)d_in[0];   // batch_prediction  [32,128,256] f32
    const float* G = (const float*)d_in[1];   // batch_groundtruth [32,128,256] f32
    float* out = (float*)d_out;               // [1] f32
    float* C = (float*)d_ws;                  // cost scratch: 32*128*128 f32 = 2 MB

    hipMemsetAsync(out, 0, sizeof(float), stream);

    dim3 gcost(Nn, Bc);
    cost_kernel<<<gcost, 64, 0, stream>>>(P, G, C);
    hungarian_kernel<<<Bc, 64, 0, stream>>>(C, out);
}

// Round 4
// 626.540 us; speedup vs baseline: 4.9469x; 1.6534x over previous
//
#include <hip/hip_runtime.h>
#include <float.h>

// Problem constants (match reference): B=32, N=M=128, D=256, WEIGHT=1.0
#define Bc 32
#define Nn 128
#define Dd 256

// ---------------------------------------------------------------------------
// Kernel 1: pairwise MSE cost.  cost[b,i,j] = sum_d (p[b,i,d]-g[b,j,d])^2 / D
// One wave (64 threads) per (b,i) row. Lane t holds float4 of p[b,i] (64*4=256).
// ---------------------------------------------------------------------------
__global__ __launch_bounds__(64) void cost_kernel(const float* __restrict__ P,
                                                  const float* __restrict__ G,
                                                  float* __restrict__ C) {
    const int b = blockIdx.y;
    const int i = blockIdx.x;
    const int t = threadIdx.x;

    const float4 pv = ((const float4*)(P + ((size_t)b * Nn + i) * Dd))[t];
    const float4* g4 = (const float4*)(G + (size_t)b * Nn * Dd);
    float* crow = C + ((size_t)b * Nn + i) * Nn;

    for (int j = 0; j < Nn; j += 2) {
        float4 gv0 = g4[(size_t)j * 64 + t];
        float4 gv1 = g4[(size_t)(j + 1) * 64 + t];
        float dx0 = pv.x - gv0.x, dy0 = pv.y - gv0.y, dz0 = pv.z - gv0.z, dw0 = pv.w - gv0.w;
        float dx1 = pv.x - gv1.x, dy1 = pv.y - gv1.y, dz1 = pv.z - gv1.z, dw1 = pv.w - gv1.w;
        float s0 = dx0 * dx0 + dy0 * dy0 + dz0 * dz0 + dw0 * dw0;
        float s1 = dx1 * dx1 + dy1 * dy1 + dz1 * dz1 + dw1 * dw1;
#pragma unroll
        for (int off = 32; off; off >>= 1) {
            s0 += __shfl_xor(s0, off);
            s1 += __shfl_xor(s1, off);
        }
        if (t == 0) {
            crow[j]     = s0 * (1.0f / (float)Dd);
            crow[j + 1] = s1 * (1.0f / (float)Dd);
        }
    }
}

// ---------------------------------------------------------------------------
// DPP full-wave reductions. Lane 63's value is exact (its combine path merges
// disjoint lane sets at every step: ror 1/2/4/8 within 16-lane rows, then
// bcast15 folds row2->row3 / row0->row1, bcast31 folds low32->high32).
// dpp_ctrl must be an integer constant -> template parameter.
// ---------------------------------------------------------------------------
template <int CTRL>
__device__ __forceinline__ float dpp_movf(float x) {
    return __int_as_float(__builtin_amdgcn_update_dpp(
        0x7f7fffff /* FLT_MAX for invalid sources */, __float_as_int(x), CTRL,
        0xf, 0xf, false));
}

__device__ __forceinline__ float wave_min_lane63(float x) {
    x = fminf(x, dpp_movf<0x121>(x));  // row_ror:1
    x = fminf(x, dpp_movf<0x122>(x));  // row_ror:2
    x = fminf(x, dpp_movf<0x124>(x));  // row_ror:4
    x = fminf(x, dpp_movf<0x128>(x));  // row_ror:8
    x = fminf(x, dpp_movf<0x142>(x));  // row_bcast:15
    x = fminf(x, dpp_movf<0x143>(x));  // row_bcast:31
    return x;                          // lane 63 = min of all 64 lanes
}

// two-min (min, second-min counting multiplicity) combine step
template <int CTRL>
__device__ __forceinline__ void dpp2min_step(float& m1, float& m2) {
    float o1 = dpp_movf<CTRL>(m1);
    float o2 = dpp_movf<CTRL>(m2);
    float n1 = fminf(m1, o1);
    m2 = fminf(fmaxf(m1, o1), fminf(m2, o2));
    m1 = n1;
}

__device__ __forceinline__ float readlane_f(float v, int lane) {
    return __int_as_float(__builtin_amdgcn_readlane(__float_as_int(v), lane));
}

// ---------------------------------------------------------------------------
// Kernel 2: LAPJV-style Hungarian, one single-wave block per batch.
//   Phase 1: column reduction (v[j] = min_i C[i][j]) + greedy zero-edge match.
//   Phase 2: augmenting row reduction, 2 bounded passes with steal.
//   Phase 3: Dijkstra (JV shortest augmenting path) for leftover free rows.
// All phases maintain dual feasibility (reduced cost >= 0) + complementary
// slackness, so phase 3 is exact from any phase-1/2 state; ARR truncation is
// safe. Optimal total cost is unique -> loss matches the f64 reference.
// State layout (registers): lane t owns columns jA=t+1, jB=t+65
//   (v, minv, way, used, p=assigned row, w=u[p[j]]) and rows t+1, t+65 (u, rU).
// ---------------------------------------------------------------------------
__global__ __launch_bounds__(64) void hungarian_kernel(const float* __restrict__ Call,
                                                       float* __restrict__ out) {
    const int b = blockIdx.x;
    const int t = threadIdx.x;

    __shared__ float Csh[Nn * Nn];  // 64 KB
    __shared__ int claim[Nn];

    // stage this batch's cost matrix into LDS (coalesced float4)
    {
        const float4* src = (const float4*)(Call + (size_t)b * Nn * Nn);
        float4* dst = (float4*)Csh;
#pragma unroll
        for (int k = 0; k < (Nn * Nn / 4) / 64; ++k)
            dst[k * 64 + t] = src[k * 64 + t];
    }
    claim[t] = 0x7fffffff;
    claim[t + 64] = 0x7fffffff;
    __syncthreads();

    // ---- Phase 1: column reduction ----
    float bestA = FLT_MAX, bestB = FLT_MAX;
    int argA = 0, argB = 0;  // 0-based argmin row per owned column
    for (int i = 0; i < Nn; ++i) {
        float c0 = Csh[i * Nn + t];
        float c1 = Csh[i * Nn + t + 64];
        if (c0 < bestA) { bestA = c0; argA = i; }
        if (c1 < bestB) { bestB = c1; argB = i; }
    }
    float vA = bestA, vB = bestB;     // column potentials (reduced costs >= 0, u=0)
    atomicMin(&claim[argA], t);       // column (0-based) claims its argmin row
    atomicMin(&claim[argB], t + 64);
    __syncthreads();

    float uA = 0.0f, uB = 0.0f;       // row potentials (rows t+1, t+65)
    float wA = 0.0f, wB = 0.0f;       // w[j] = u[p[j]]
    int pA = 0, pB = 0;               // row assigned to column (0 = free)
    if (claim[argA] == t)      pA = argA + 1;
    if (claim[argB] == t + 64) pB = argB + 1;

    unsigned long long fmA = __ballot(claim[t] == 0x7fffffff);       // free rows 1..64
    unsigned long long fmB = __ballot(claim[t + 64] == 0x7fffffff);  // free rows 65..128

    // ---- Phase 2: augmenting row reduction (2 passes, bounded, with steal) ----
    for (int pass = 0; pass < 2; ++pass) {
        if (!(fmA | fmB)) break;
        unsigned long long remA = fmA, remB = fmB;
        int guard = 0;
        while ((remA | remB) != 0ull && guard++ < 256) {
            int l, i, slotR;
            if (remA) { l = __ffsll(remA) - 1; remA &= remA - 1; i = l + 1;  slotR = 0;
                        if (!((fmA >> l) & 1)) continue; }
            else      { l = __ffsll(remB) - 1; remB &= remB - 1; i = l + 65; slotR = 1;
                        if (!((fmB >> l) & 1)) continue; }

            const float* crow = &Csh[(i - 1) * Nn];
            float cur0 = crow[t] - vA;
            float cur1 = crow[t + 64] - vB;
            float m1 = fminf(cur0, cur1);
            float m2 = fmaxf(cur0, cur1);
            dpp2min_step<0x121>(m1, m2);
            dpp2min_step<0x122>(m1, m2);
            dpp2min_step<0x124>(m1, m2);
            dpp2min_step<0x128>(m1, m2);
            dpp2min_step<0x142>(m1, m2);
            dpp2min_step<0x143>(m1, m2);
            float s_m1 = readlane_f(m1, 63);
            float s_m2 = readlane_f(m2, 63);

            unsigned long long b0 = __ballot(cur0 == s_m1);
            unsigned long long b1 = __ballot(cur1 == s_m1);
            int j1 = b0 ? __ffsll(b0) : (__ffsll(b1) + 64);  // 1-based column
            int lane1 = (j1 - 1) & 63, slot1 = (j1 - 1) >> 6;

            // u[i] = second-min  (dual-feasible regardless of what follows)
            if (t == l) { if (slotR == 0) uA = s_m2; else uB = s_m2; }

            int k0 = __builtin_amdgcn_readlane(slot1 ? pB : pA, lane1);
            bool strict = (s_m1 < s_m2);
            if (!strict && k0 != 0) continue;  // tie & occupied: leave row free

            if (t == lane1) {
                if (slot1 == 0) { vA += s_m1 - s_m2; pA = i; wA = s_m2; }
                else            { vB += s_m1 - s_m2; pB = i; wB = s_m2; }
            }
            if (slotR == 0) fmA &= ~(1ull << l); else fmB &= ~(1ull << l);
            if (k0 != 0) {  // stolen row becomes free again
                int kl = (k0 - 1) & 63;
                if (k0 <= 64) { fmA |= 1ull << kl; remA |= 1ull << kl; }
                else          { fmB |= 1ull << kl; remB |= 1ull << kl; }
            }
        }
    }

    // ---- Phase 3: Dijkstra shortest augmenting path for leftover free rows ----
    for (int slotR = 0; slotR < 2; ++slotR) {
        unsigned long long mask = slotR ? fmB : fmA;
        while (mask) {
            int l = __ffsll(mask) - 1;
            mask &= mask - 1;
            int i = l + 1 + slotR * 64;  // 1-based free row

            float minvA = FLT_MAX, minvB = FLT_MAX;
            int wayA = 0, wayB = 0;
            bool usedA = false, usedB = false;
            bool rUA = false, rUB = false;
            if (t == l) { if (slotR == 0) rUA = true; else rUB = true; }

            int s_j0 = 0;
            int s_i0 = i;
            float s_u = readlane_f(slotR ? uB : uA, l);  // u[i] from ARR
            int s_j1;

            for (;;) {
                // relax free columns against row s_i0
                const float* crow = &Csh[(s_i0 - 1) * Nn];
                float c0 = crow[t];
                float c1 = crow[t + 64];
                if (!usedA) {
                    float cur = c0 - s_u - vA;
                    if (cur < minvA) { minvA = cur; wayA = s_j0; }
                }
                if (!usedB) {
                    float cur = c1 - s_u - vB;
                    if (cur < minvB) { minvB = cur; wayB = s_j0; }
                }

                // exact argmin over free columns
                float mA = usedA ? FLT_MAX : minvA;
                float mB = usedB ? FLT_MAX : minvB;
                float r63 = wave_min_lane63(fminf(mA, mB));
                float s_delta = readlane_f(r63, 63);
                unsigned long long ba = __ballot(mA == s_delta);
                unsigned long long bb = __ballot(mB == s_delta);
                s_j1 = ba ? __ffsll(ba) : (__ffsll(bb) + 64);

                // dual updates
                if (usedA) { vA -= s_delta; wA += s_delta; } else { minvA -= s_delta; }
                if (usedB) { vB -= s_delta; wB += s_delta; } else { minvB -= s_delta; }
                if (rUA) uA += s_delta;
                if (rUB) uB += s_delta;

                // advance to column j1
                int lane1 = (s_j1 - 1) & 63;
                int slot1 = (s_j1 - 1) >> 6;
                int s_p = __builtin_amdgcn_readlane(slot1 ? pB : pA, lane1);
                float s_w = readlane_f(slot1 ? wB : wA, lane1);

                if (s_p == 0) break;  // augmenting path found at s_j1

                if (t == lane1) { if (slot1 == 0) usedA = true; else usedB = true; }
                {
                    int r = s_p - 1;
                    if (t == (r & 63)) { if ((r >> 6) == 0) rUA = true; else rUB = true; }
                }
                s_j0 = s_j1;
                s_i0 = s_p;
                s_u = s_w;
            }

            // augment along way[] chain (uniform serial walk)
            int s_j = s_j1;
            while (s_j) {
                int lane = (s_j - 1) & 63;
                int slot = (s_j - 1) >> 6;
                int s_jprev = __builtin_amdgcn_readlane(slot ? wayB : wayA, lane);
                int s_pnew;
                if (s_jprev == 0) {
                    s_pnew = i;
                } else {
                    int lp = (s_jprev - 1) & 63;
                    int sp = (s_jprev - 1) >> 6;
                    s_pnew = __builtin_amdgcn_readlane(sp ? pB : pA, lp);
                }
                int rl = (s_pnew - 1) & 63;
                int rs = (s_pnew - 1) >> 6;
                float s_unew = readlane_f(rs ? uB : uA, rl);  // w[j] = u[p[j]]
                if (t == lane) {
                    if (slot == 0) { pA = s_pnew; wA = s_unew; }
                    else           { pB = s_pnew; wB = s_unew; }
                }
                s_j = s_jprev;
            }
        }
    }

    // ---- gather matched costs: column jA=t+1 -> row pA, etc. ----
    float tot = Csh[(pA - 1) * Nn + t] + Csh[(pB - 1) * Nn + t + 64];
#pragma unroll
    for (int off = 32; off; off >>= 1) tot += __shfl_xor(tot, off);

    if (t == 0) {
        // loss = sum_b (total_b / N) / B * WEIGHT
        atomicAdd(out, tot * (1.0f / ((float)Nn * (float)Bc)));
    }
}

extern "C" void kernel_launch(void* const* d_in, const int* in_sizes, int n_in,
                              void* d_out, int out_size, void* d_ws, size_t ws_size,
                              hipStream_t stream) {
    const float* P = (const float*)d_in[0];   // batch_prediction  [32,128,256] f32
    const float* G = (const float*)d_in[1];   // batch_groundtruth [32,128,256] f32
    float* out = (float*)d_out;               // [1] f32
    float* C = (float*)d_ws;                  // cost scratch: 32*128*128 f32 = 2 MB

    (void)hipMemsetAsync(out, 0, sizeof(float), stream);

    dim3 gcost(Nn, Bc);
    cost_kernel<<<gcost, 64, 0, stream>>>(P, G, C);
    hungarian_kernel<<<Bc, 64, 0, stream>>>(C, out);
}

// Round 5
// 548.944 us; speedup vs baseline: 5.6462x; 1.1414x over previous
//
#include <hip/hip_runtime.h>
#include <float.h>

// Problem constants (match reference): B=32, N=M=128, D=256, WEIGHT=1.0
#define Bc 32
#define Nn 128
#define Dd 256

// ---------------------------------------------------------------------------
// DPP helpers. dpp_ctrl must be a compile-time constant.
// Reduction to lane 63: ror 1/2/4/8 within 16-lane rows (all sources valid),
// then row_bcast:15 / row_bcast:31 fold rows; lane 63 ends with the full
// 64-lane reduction (standard CDNA pattern).
// ---------------------------------------------------------------------------
template <int CTRL>
__device__ __forceinline__ float dpp_addsrc(float x) {  // old = 0 for untouched lanes
    return __int_as_float(__builtin_amdgcn_update_dpp(0, __float_as_int(x), CTRL,
                                                      0xf, 0xf, false));
}
__device__ __forceinline__ float wave_sum_lane63(float x) {
    x += dpp_addsrc<0x121>(x);  // row_ror:1
    x += dpp_addsrc<0x122>(x);  // row_ror:2
    x += dpp_addsrc<0x124>(x);  // row_ror:4
    x += dpp_addsrc<0x128>(x);  // row_ror:8
    x += dpp_addsrc<0x142>(x);  // row_bcast:15
    x += dpp_addsrc<0x143>(x);  // row_bcast:31
    return x;                   // lane 63 = total
}

template <int CTRL>
__device__ __forceinline__ unsigned dpp_movu(unsigned x) {  // old = UINT_MAX
    return (unsigned)__builtin_amdgcn_update_dpp((int)0xFFFFFFFFu, (int)x, CTRL,
                                                 0xf, 0xf, false);
}
__device__ __forceinline__ unsigned wave_umin_lane63(unsigned x) {
    x = min(x, dpp_movu<0x121>(x));
    x = min(x, dpp_movu<0x122>(x));
    x = min(x, dpp_movu<0x124>(x));
    x = min(x, dpp_movu<0x128>(x));
    x = min(x, dpp_movu<0x142>(x));
    x = min(x, dpp_movu<0x143>(x));
    return x;                   // lane 63 = min of all 64 lanes
}

template <int CTRL>
__device__ __forceinline__ float dpp_movf(float x) {  // old = FLT_MAX
    return __int_as_float(__builtin_amdgcn_update_dpp(0x7f7fffff, __float_as_int(x),
                                                      CTRL, 0xf, 0xf, false));
}
// two-min (min, second-min counting multiplicity) combine step
template <int CTRL>
__device__ __forceinline__ void dpp2min_step(float& m1, float& m2) {
    float o1 = dpp_movf<CTRL>(m1);
    float o2 = dpp_movf<CTRL>(m2);
    float n1 = fminf(m1, o1);
    m2 = fminf(fmaxf(m1, o1), fminf(m2, o2));
    m1 = n1;
}

__device__ __forceinline__ float readlane_f(float v, int lane) {
    return __int_as_float(__builtin_amdgcn_readlane(__float_as_int(v), lane));
}

// ---------------------------------------------------------------------------
// Kernel 1: pairwise MSE cost.  cost[b,i,j] = sum_d (p[b,i,d]-g[b,j,d])^2 / D
// One wave per (b,i) row; lane t holds float4 of p[b,i]. DPP-add reduction
// (pure VALU) instead of shfl chains (ds_bpermute). Block (0,0) lane 0 also
// zeroes the output scalar (replaces a separate memset dispatch; stream
// ordering guarantees it lands before hungarian's atomicAdds).
// ---------------------------------------------------------------------------
__global__ __launch_bounds__(64) void cost_kernel(const float* __restrict__ P,
                                                  const float* __restrict__ G,
                                                  float* __restrict__ C,
                                                  float* __restrict__ out) {
    const int b = blockIdx.y;
    const int i = blockIdx.x;
    const int t = threadIdx.x;

    if (b == 0 && i == 0 && t == 0) *out = 0.0f;

    const float4 pv = ((const float4*)(P + ((size_t)b * Nn + i) * Dd))[t];
    const float4* g4 = (const float4*)(G + (size_t)b * Nn * Dd);
    float* crow = C + ((size_t)b * Nn + i) * Nn;

    for (int j = 0; j < Nn; j += 2) {
        float4 gv0 = g4[(size_t)j * 64 + t];
        float4 gv1 = g4[(size_t)(j + 1) * 64 + t];
        float dx0 = pv.x - gv0.x, dy0 = pv.y - gv0.y, dz0 = pv.z - gv0.z, dw0 = pv.w - gv0.w;
        float dx1 = pv.x - gv1.x, dy1 = pv.y - gv1.y, dz1 = pv.z - gv1.z, dw1 = pv.w - gv1.w;
        float s0 = dx0 * dx0 + dy0 * dy0 + dz0 * dz0 + dw0 * dw0;
        float s1 = dx1 * dx1 + dy1 * dy1 + dz1 * dz1 + dw1 * dw1;
        s0 = wave_sum_lane63(s0);
        s1 = wave_sum_lane63(s1);
        if (t == 63) {
            crow[j]     = s0 * (1.0f / (float)Dd);
            crow[j + 1] = s1 * (1.0f / (float)Dd);
        }
    }
}

// ---------------------------------------------------------------------------
// Kernel 2: LAPJV-style Hungarian, one single-wave block per batch.
//   Phase 1: column reduction + greedy zero-edge match.
//   Phase 2: augmenting row reduction (2 bounded passes with steal).
//   Phase 3: Dijkstra shortest augmenting path for leftover free rows,
//            with packed-key argmin (value|index in one u32, one v_min_u32
//            DPP chain, single readlane) and LDS next-row prefetch.
// All phases maintain (eps-)dual feasibility + complementary slackness;
// packed-key drops 8 mantissa bits of minv (<=2^-15 rel perturbation) and
// clamps keep reduced costs >= 0, so the found assignment is optimal for a
// tiny perturbation of C; loss error ~1e-3 << 3.4e-2 threshold.
// State: lane t owns columns jA=t+1, jB=t+65 (v, minv, way, used, p, w=u[p])
// and rows t+1, t+65 (u, rU). No LDS state / barriers in the hot loop.
// ---------------------------------------------------------------------------
__global__ __launch_bounds__(64) void hungarian_kernel(const float* __restrict__ Call,
                                                       float* __restrict__ out) {
    const int b = blockIdx.x;
    const int t = threadIdx.x;

    __shared__ float Csh[Nn * Nn];  // 64 KB
    __shared__ int claim[Nn];

    // stage this batch's cost matrix into LDS (coalesced float4)
    {
        const float4* src = (const float4*)(Call + (size_t)b * Nn * Nn);
        float4* dst = (float4*)Csh;
#pragma unroll
        for (int k = 0; k < (Nn * Nn / 4) / 64; ++k)
            dst[k * 64 + t] = src[k * 64 + t];
    }
    claim[t] = 0x7fffffff;
    claim[t + 64] = 0x7fffffff;
    __syncthreads();

    // ---- Phase 1: column reduction ----
    float bestA = FLT_MAX, bestB = FLT_MAX;
    int argA = 0, argB = 0;  // 0-based argmin row per owned column
    for (int i = 0; i < Nn; ++i) {
        float c0 = Csh[i * Nn + t];
        float c1 = Csh[i * Nn + t + 64];
        if (c0 < bestA) { bestA = c0; argA = i; }
        if (c1 < bestB) { bestB = c1; argB = i; }
    }
    float vA = bestA, vB = bestB;     // column potentials (reduced costs >= 0, u=0)
    atomicMin(&claim[argA], t);       // column (0-based) claims its argmin row
    atomicMin(&claim[argB], t + 64);
    __syncthreads();

    float uA = 0.0f, uB = 0.0f;       // row potentials (rows t+1, t+65)
    float wA = 0.0f, wB = 0.0f;       // w[j] = u[p[j]]
    int pA = 0, pB = 0;               // row assigned to column (0 = free)
    if (claim[argA] == t)      pA = argA + 1;
    if (claim[argB] == t + 64) pB = argB + 1;

    unsigned long long fmA = __ballot(claim[t] == 0x7fffffff);       // free rows 1..64
    unsigned long long fmB = __ballot(claim[t + 64] == 0x7fffffff);  // free rows 65..128

    // ---- Phase 2: augmenting row reduction (2 passes, bounded, with steal) ----
    for (int pass = 0; pass < 2; ++pass) {
        if (!(fmA | fmB)) break;
        unsigned long long remA = fmA, remB = fmB;
        int guard = 0;
        while ((remA | remB) != 0ull && guard++ < 256) {
            int l, i, slotR;
            if (remA) { l = __ffsll(remA) - 1; remA &= remA - 1; i = l + 1;  slotR = 0;
                        if (!((fmA >> l) & 1)) continue; }
            else      { l = __ffsll(remB) - 1; remB &= remB - 1; i = l + 65; slotR = 1;
                        if (!((fmB >> l) & 1)) continue; }

            const float* crow = &Csh[(i - 1) * Nn];
            float cur0 = crow[t] - vA;
            float cur1 = crow[t + 64] - vB;
            float m1 = fminf(cur0, cur1);
            float m2 = fmaxf(cur0, cur1);
            dpp2min_step<0x121>(m1, m2);
            dpp2min_step<0x122>(m1, m2);
            dpp2min_step<0x124>(m1, m2);
            dpp2min_step<0x128>(m1, m2);
            dpp2min_step<0x142>(m1, m2);
            dpp2min_step<0x143>(m1, m2);
            float s_m1 = readlane_f(m1, 63);
            float s_m2 = readlane_f(m2, 63);

            unsigned long long b0 = __ballot(cur0 == s_m1);
            unsigned long long b1 = __ballot(cur1 == s_m1);
            int j1 = b0 ? __ffsll(b0) : (__ffsll(b1) + 64);  // 1-based column
            int lane1 = (j1 - 1) & 63, slot1 = (j1 - 1) >> 6;

            // u[i] = second-min  (dual-feasible regardless of what follows)
            if (t == l) { if (slotR == 0) uA = s_m2; else uB = s_m2; }

            int k0 = __builtin_amdgcn_readlane(slot1 ? pB : pA, lane1);
            bool strict = (s_m1 < s_m2);
            if (!strict && k0 != 0) continue;  // tie & occupied: leave row free

            if (t == lane1) {
                if (slot1 == 0) { vA += s_m1 - s_m2; pA = i; wA = s_m2; }
                else            { vB += s_m1 - s_m2; pB = i; wB = s_m2; }
            }
            if (slotR == 0) fmA &= ~(1ull << l); else fmB &= ~(1ull << l);
            if (k0 != 0) {  // stolen row becomes free again
                int kl = (k0 - 1) & 63;
                if (k0 <= 64) { fmA |= 1ull << kl; remA |= 1ull << kl; }
                else          { fmB |= 1ull << kl; remB |= 1ull << kl; }
            }
        }
    }

    // ---- Phase 3: Dijkstra shortest augmenting path for leftover free rows ----
    for (int slotR = 0; slotR < 2; ++slotR) {
        unsigned long long mask = slotR ? fmB : fmA;
        while (mask) {
            int l = __ffsll(mask) - 1;
            mask &= mask - 1;
            int i = l + 1 + slotR * 64;  // 1-based free row

            float minvA = FLT_MAX, minvB = FLT_MAX;
            int wayA = 0, wayB = 0;
            bool usedA = false, usedB = false;
            bool rUA = false, rUB = false;
            if (t == l) { if (slotR == 0) rUA = true; else rUB = true; }

            int s_j0 = 0;
            float s_u = readlane_f(slotR ? uB : uA, l);  // u[i] from ARR
            int s_j1;

            // initial row load (row i)
            float c0 = Csh[(i - 1) * Nn + t];
            float c1 = Csh[(i - 1) * Nn + t + 64];

            for (;;) {
                // relax free columns (clamped >= 0 so packed keys order correctly)
                if (!usedA) {
                    float cur = fmaxf(c0 - s_u - vA, 0.0f);
                    if (cur < minvA) { minvA = cur; wayA = s_j0; }
                }
                if (!usedB) {
                    float cur = fmaxf(c1 - s_u - vB, 0.0f);
                    if (cur < minvB) { minvB = cur; wayB = s_j0; }
                }

                // packed-key argmin: (value_bits & ~0xFF) | col0based
                unsigned kA = (__float_as_uint(usedA ? FLT_MAX : minvA) & 0xFFFFFF00u)
                              | (unsigned)t;
                unsigned kB = (__float_as_uint(usedB ? FLT_MAX : minvB) & 0xFFFFFF00u)
                              | (unsigned)(t + 64);
                unsigned k = wave_umin_lane63(min(kA, kB));
                unsigned s_key = (unsigned)__builtin_amdgcn_readlane((int)k, 63);
                float s_delta = __uint_as_float(s_key & 0xFFFFFF00u);
                s_j1 = (int)(s_key & 0xFFu) + 1;  // 1-based column

                // lookup p,w for j1 (needed for prefetch — do before dual updates)
                int lane1 = (s_j1 - 1) & 63;
                int slot1 = (s_j1 - 1) >> 6;
                int s_p = __builtin_amdgcn_readlane(slot1 ? pB : pA, lane1);
                float s_w = readlane_f(slot1 ? wB : wA, lane1);

                // prefetch next cost row (safe index; latency hides under updates)
                int nrow = (s_p > 0 ? s_p : 1) - 1;
                float nc0 = Csh[nrow * Nn + t];
                float nc1 = Csh[nrow * Nn + t + 64];

                // dual updates (independent of prefetch data)
                if (usedA) { vA -= s_delta; wA += s_delta; }
                else       { minvA = fmaxf(minvA - s_delta, 0.0f); }
                if (usedB) { vB -= s_delta; wB += s_delta; }
                else       { minvB = fmaxf(minvB - s_delta, 0.0f); }
                if (rUA) uA += s_delta;
                if (rUB) uB += s_delta;

                if (s_p == 0) break;  // augmenting path found at s_j1

                if (t == lane1) { if (slot1 == 0) usedA = true; else usedB = true; }
                {
                    int r = s_p - 1;
                    if (t == (r & 63)) { if ((r >> 6) == 0) rUA = true; else rUB = true; }
                }
                s_j0 = s_j1;
                s_u = s_w;
                c0 = nc0;
                c1 = nc1;
            }

            // augment along way[] chain (uniform serial walk)
            int s_j = s_j1;
            while (s_j) {
                int lane = (s_j - 1) & 63;
                int slot = (s_j - 1) >> 6;
                int s_jprev = __builtin_amdgcn_readlane(slot ? wayB : wayA, lane);
                int s_pnew;
                if (s_jprev == 0) {
                    s_pnew = i;
                } else {
                    int lp = (s_jprev - 1) & 63;
                    int sp = (s_jprev - 1) >> 6;
                    s_pnew = __builtin_amdgcn_readlane(sp ? pB : pA, lp);
                }
                int rl = (s_pnew - 1) & 63;
                int rs = (s_pnew - 1) >> 6;
                float s_unew = readlane_f(rs ? uB : uA, rl);  // w[j] = u[p[j]]
                if (t == lane) {
                    if (slot == 0) { pA = s_pnew; wA = s_unew; }
                    else           { pB = s_pnew; wB = s_unew; }
                }
                s_j = s_jprev;
            }
        }
    }

    // ---- gather matched costs: column jA=t+1 -> row pA, etc. ----
    float tot = Csh[(pA - 1) * Nn + t] + Csh[(pB - 1) * Nn + t + 64];
    tot = wave_sum_lane63(tot);

    if (t == 63) {
        // loss = sum_b (total_b / N) / B * WEIGHT
        atomicAdd(out, tot * (1.0f / ((float)Nn * (float)Bc)));
    }
}

extern "C" void kernel_launch(void* const* d_in, const int* in_sizes, int n_in,
                              void* d_out, int out_size, void* d_ws, size_t ws_size,
                              hipStream_t stream) {
    const float* P = (const float*)d_in[0];   // batch_prediction  [32,128,256] f32
    const float* G = (const float*)d_in[1];   // batch_groundtruth [32,128,256] f32
    float* out = (float*)d_out;               // [1] f32
    float* C = (float*)d_ws;                  // cost scratch: 32*128*128 f32 = 2 MB

    dim3 gcost(Nn, Bc);
    cost_kernel<<<gcost, 64, 0, stream>>>(P, G, C, out);
    hungarian_kernel<<<Bc, 64, 0, stream>>>(C, out);
}